// Round 1
// baseline (55499.481 us; speedup 1.0000x reference)
//
#include <hip/hip_runtime.h>
#include <math.h>

// RNNModel_8701603741907 — round 0: correct fp32 baseline.
// Structure: gather emb/ctx -> Zx GEMM -> 32x lstm_step (x2 layers) ->
// gate GEMM(sigmoid) -> 5x transed GEMM -> fused logits (552 GF) ->
// row softmax -> word GEMM (409 GF) -> copy h/c.
// All heavy GEMMs: fp32 64x64 tile, KC=32, 4x4 micro, 256 thr.

#define T_ 32
#define B_ 32
#define H_ 512
#define V_ 10000
#define S_ 2186
#define Z_ 20000
#define K_ 5
#define N_ (T_*B_)      // 1024
#define G4 (4*H_)       // 2048

__device__ __forceinline__ float sigm(float x) { return 1.f / (1.f + expf(-x)); }

// ---------------- generic fp32 GEMM: C[M,N] = A[M,K] @ B (+bias)(+act) ------
// BT=true : B is [N][K] row-major (i.e. C = A @ B^T)
// BT=false: B is [K][N] row-major
// M must be a multiple of 64; K a multiple of 32. N guarded.
template<bool BT, int ACT>
__global__ __launch_bounds__(256) void gemm64(
    const float* __restrict__ A, const float* __restrict__ B,
    const float* __restrict__ b1, const float* __restrict__ b2,
    float* __restrict__ C, int M, int Nn, int Kk)
{
    const int n0 = blockIdx.x * 64;
    const int m0 = blockIdx.y * 64;
    const int tid = threadIdx.x;
    const int tx = tid & 15, ty = tid >> 4;
    __shared__ __align__(16) float As[32][68];
    __shared__ __align__(16) float Bs[32][68];
    float acc[4][4] = {};
    for (int kb = 0; kb < Kk; kb += 32) {
        #pragma unroll
        for (int l = 0; l < 8; ++l) {
            int lin = tid + l * 256;
            int i = lin >> 5, kk = lin & 31;
            As[kk][i] = A[(size_t)(m0 + i) * Kk + kb + kk];
        }
        #pragma unroll
        for (int l = 0; l < 8; ++l) {
            int lin = tid + l * 256;
            if (BT) {
                int j = lin >> 5, kk = lin & 31;
                int n = n0 + j;
                Bs[kk][j] = (n < Nn) ? B[(size_t)n * Kk + kb + kk] : 0.f;
            } else {
                int kk = lin >> 6, j = lin & 63;
                int n = n0 + j;
                Bs[kk][j] = (n < Nn) ? B[(size_t)(kb + kk) * Nn + n] : 0.f;
            }
        }
        __syncthreads();
        #pragma unroll
        for (int kk = 0; kk < 32; ++kk) {
            float4 av = *reinterpret_cast<const float4*>(&As[kk][ty * 4]);
            float4 bv = *reinterpret_cast<const float4*>(&Bs[kk][tx * 4]);
            float a[4] = {av.x, av.y, av.z, av.w};
            float b[4] = {bv.x, bv.y, bv.z, bv.w};
            #pragma unroll
            for (int r = 0; r < 4; ++r)
                #pragma unroll
                for (int c = 0; c < 4; ++c)
                    acc[r][c] = fmaf(a[r], b[c], acc[r][c]);
        }
        __syncthreads();
    }
    #pragma unroll
    for (int r = 0; r < 4; ++r) {
        int m = m0 + ty * 4 + r;
        #pragma unroll
        for (int c = 0; c < 4; ++c) {
            int n = n0 + tx * 4 + c;
            if (n < Nn) {
                float v = acc[r][c];
                if (b1) v += b1[n];
                if (b2) v += b2[n];
                if (ACT == 1) v = sigm(v);
                C[(size_t)m * Nn + n] = v;
            }
        }
    }
}

// ---------------- LSTM step: z = zx_t + h_prev @ Whh^T; gates; h,c ----------
// grid (32,4): blockIdx.x = 16-wide hcol tile, blockIdx.y = 8-wide batch tile.
// Block computes 8 b x 16 hcol x 4 gates = 512 z values, then pointwise.
__global__ __launch_bounds__(256) void lstm_step(
    const float* __restrict__ zx_t,   // [B][4H], biases already included
    const float* __restrict__ h_prev, // [B][H]
    const float* __restrict__ Whh,    // [4H][H]
    const float* __restrict__ c_in,   // [B][H]
    float* __restrict__ c_out,        // [B][H]
    float* __restrict__ h_out)        // [B][H] (== y[t])
{
    const int hc0 = blockIdx.x * 16;
    const int b0 = blockIdx.y * 8;
    const int tid = threadIdx.x;
    __shared__ float hs[32][9];
    __shared__ float ws[32][68];
    __shared__ float zs[8][64];
    const int cl = tid & 63;            // 0..63: g = cl>>4, hc = cl&15
    const int r0 = tid >> 6;            // rows r0 and r0+4
    const int g = cl >> 4, hc = cl & 15;
    const int j = g * H_ + hc0 + hc;    // Whh / zx column
    float acc0 = 0.f, acc1 = 0.f;
    for (int kb = 0; kb < H_; kb += 32) {
        {
            int bl = tid >> 5, kk = tid & 31;
            hs[kk][bl] = h_prev[(size_t)(b0 + bl) * H_ + kb + kk];
        }
        #pragma unroll
        for (int l = 0; l < 8; ++l) {
            int lin = tid + l * 256;
            int cc = lin >> 5, kk = lin & 31;
            int gg = cc >> 4, hh = cc & 15;
            ws[kk][cc] = Whh[(size_t)(gg * H_ + hc0 + hh) * H_ + kb + kk];
        }
        __syncthreads();
        #pragma unroll
        for (int kk = 0; kk < 32; ++kk) {
            float w = ws[kk][cl];
            acc0 = fmaf(hs[kk][r0], w, acc0);
            acc1 = fmaf(hs[kk][r0 + 4], w, acc1);
        }
        __syncthreads();
    }
    zs[r0][cl]     = acc0 + zx_t[(size_t)(b0 + r0) * G4 + j];
    zs[r0 + 4][cl] = acc1 + zx_t[(size_t)(b0 + r0 + 4) * G4 + j];
    __syncthreads();
    if (tid < 128) {
        int bl = tid >> 4, hh = tid & 15;
        float zi = zs[bl][hh];
        float zf = zs[bl][16 + hh];
        float zg = zs[bl][32 + hh];
        float zo = zs[bl][48 + hh];
        size_t idx = (size_t)(b0 + bl) * H_ + hc0 + hh;
        float cp = c_in[idx];
        float cn = sigm(zf) * cp + sigm(zi) * tanhf(zg);
        float hn = sigm(zo) * tanhf(cn);
        c_out[idx] = cn;
        h_out[idx] = hn;
    }
}

// ---------------- fused logits: sum_k (transed@ctx) * (coeff@M1) + bias -----
// logits[n][z] = sum_k (sum_h transed[k][n][h]*ctxT[z][h])
//                    * (sum_s gate[n][s]*smw[k][s]*M1[s][z])  + sense_bias[z]
__global__ __launch_bounds__(256) void fused_logits(
    const float* __restrict__ transed, const float* __restrict__ ctxT,
    const float* __restrict__ gate, const float* __restrict__ smw,
    const float* __restrict__ M1, const float* __restrict__ sense_bias,
    float* __restrict__ logits)
{
    const int z0 = blockIdx.x * 64;
    const int n0 = blockIdx.y * 64;
    const int tid = threadIdx.x;
    const int tx = tid & 15, ty = tid >> 4;
    __shared__ __align__(16) float As[32][68];
    __shared__ __align__(16) float Bs[32][68];
    float tot[4][4] = {};
    for (int k = 0; k < K_; ++k) {
        // phase 1: acc1 = transed[k] @ ctxT^T  (K = H_)
        float acc1[4][4] = {};
        const float* Ak = transed + (size_t)k * N_ * H_;
        for (int hb = 0; hb < H_; hb += 32) {
            #pragma unroll
            for (int l = 0; l < 8; ++l) {
                int lin = tid + l * 256;
                int i = lin >> 5, kk = lin & 31;
                As[kk][i] = Ak[(size_t)(n0 + i) * H_ + hb + kk];
                int zz = z0 + i;
                Bs[kk][i] = (zz < Z_) ? ctxT[(size_t)zz * H_ + hb + kk] : 0.f;
            }
            __syncthreads();
            #pragma unroll
            for (int kk = 0; kk < 32; ++kk) {
                float4 av = *reinterpret_cast<const float4*>(&As[kk][ty * 4]);
                float4 bv = *reinterpret_cast<const float4*>(&Bs[kk][tx * 4]);
                float a[4] = {av.x, av.y, av.z, av.w};
                float b[4] = {bv.x, bv.y, bv.z, bv.w};
                #pragma unroll
                for (int r = 0; r < 4; ++r)
                    #pragma unroll
                    for (int c = 0; c < 4; ++c)
                        acc1[r][c] = fmaf(a[r], b[c], acc1[r][c]);
            }
            __syncthreads();
        }
        // phase 2: acc2 = (gate*smw[k]) @ M1  (K = S_, tail-guarded)
        float acc2[4][4] = {};
        const float* smk = smw + (size_t)k * S_;
        for (int sb = 0; sb < S_; sb += 32) {
            #pragma unroll
            for (int l = 0; l < 8; ++l) {
                int lin = tid + l * 256;
                int i = lin >> 5, kk = lin & 31;
                int s = sb + kk;
                As[kk][i] = (s < S_) ? gate[(size_t)(n0 + i) * S_ + s] * smk[s] : 0.f;
            }
            #pragma unroll
            for (int l = 0; l < 8; ++l) {
                int lin = tid + l * 256;
                int kk = lin >> 6, jj = lin & 63;
                int s = sb + kk;
                int zz = z0 + jj;
                Bs[kk][jj] = (s < S_ && zz < Z_) ? M1[(size_t)s * Z_ + zz] : 0.f;
            }
            __syncthreads();
            #pragma unroll
            for (int kk = 0; kk < 32; ++kk) {
                float4 av = *reinterpret_cast<const float4*>(&As[kk][ty * 4]);
                float4 bv = *reinterpret_cast<const float4*>(&Bs[kk][tx * 4]);
                float a[4] = {av.x, av.y, av.z, av.w};
                float b[4] = {bv.x, bv.y, bv.z, bv.w};
                #pragma unroll
                for (int r = 0; r < 4; ++r)
                    #pragma unroll
                    for (int c = 0; c < 4; ++c)
                        acc2[r][c] = fmaf(a[r], b[c], acc2[r][c]);
            }
            __syncthreads();
        }
        #pragma unroll
        for (int r = 0; r < 4; ++r)
            #pragma unroll
            for (int c = 0; c < 4; ++c)
                tot[r][c] = fmaf(acc1[r][c], acc2[r][c], tot[r][c]);
    }
    #pragma unroll
    for (int r = 0; r < 4; ++r) {
        int n = n0 + ty * 4 + r;
        #pragma unroll
        for (int c = 0; c < 4; ++c) {
            int z = z0 + tx * 4 + c;
            if (z < Z_)
                logits[(size_t)n * Z_ + z] = tot[r][c] + sense_bias[z];
        }
    }
}

// ---------------- row softmax over Z, in place ------------------------------
__global__ __launch_bounds__(256) void softmax_rows(float* __restrict__ p)
{
    const int n = blockIdx.x;
    float* row = p + (size_t)n * Z_;
    const int tid = threadIdx.x;
    __shared__ float red[4], red2[4];
    float m = -1e30f;
    for (int i = tid; i < Z_; i += 256) m = fmaxf(m, row[i]);
    #pragma unroll
    for (int off = 32; off; off >>= 1) m = fmaxf(m, __shfl_down(m, off, 64));
    if ((tid & 63) == 0) red[tid >> 6] = m;
    __syncthreads();
    m = fmaxf(fmaxf(red[0], red[1]), fmaxf(red[2], red[3]));
    float s = 0.f;
    for (int i = tid; i < Z_; i += 256) {
        float e = expf(row[i] - m);
        row[i] = e;
        s += e;
    }
    #pragma unroll
    for (int off = 32; off; off >>= 1) s += __shfl_down(s, off, 64);
    if ((tid & 63) == 0) red2[tid >> 6] = s;
    __syncthreads();
    float inv = 1.f / (red2[0] + red2[1] + red2[2] + red2[3]);
    for (int i = tid; i < Z_; i += 256) row[i] *= inv;
}

// ---------------- small helpers ---------------------------------------------
__global__ void smw_softmax(const float* __restrict__ mw, float* __restrict__ smw)
{
    int s = blockIdx.x * 256 + threadIdx.x;
    if (s >= S_) return;
    float w[K_];
    float m = -1e30f;
    for (int k = 0; k < K_; ++k) { w[k] = mw[k * S_ + s]; m = fmaxf(m, w[k]); }
    float sum = 0.f;
    for (int k = 0; k < K_; ++k) { w[k] = expf(w[k] - m); sum += w[k]; }
    float inv = 1.f / sum;
    for (int k = 0; k < K_; ++k) smw[k * S_ + s] = w[k] * inv;
}

__global__ void gather_rows4(const float* __restrict__ E, const int* __restrict__ idx,
                             float* __restrict__ out, int rows)
{
    int t = blockIdx.x * 256 + threadIdx.x;
    const int per = H_ / 4;  // 128 float4 per row
    if (t >= rows * per) return;
    int r = t / per, q = t % per;
    const float4* src = reinterpret_cast<const float4*>(E + (size_t)idx[r] * H_);
    reinterpret_cast<float4*>(out + (size_t)r * H_)[q] = src[q];
}

__global__ void copy_hc(const float* __restrict__ y0, const float* __restrict__ y1,
                        const float* __restrict__ cb0, const float* __restrict__ cb1,
                        float* __restrict__ out_h, float* __restrict__ out_c)
{
    int i = blockIdx.x * 256 + threadIdx.x;
    if (i >= B_ * H_) return;
    out_h[i]            = y0[(size_t)(T_ - 1) * B_ * H_ + i];
    out_h[B_ * H_ + i]  = y1[(size_t)(T_ - 1) * B_ * H_ + i];
    out_c[i]            = cb0[i];
    out_c[B_ * H_ + i]  = cb1[i];
}

// ---------------- launch ----------------------------------------------------
extern "C" void kernel_launch(void* const* d_in, const int* in_sizes, int n_in,
                              void* d_out, int out_size, void* d_ws, size_t ws_size,
                              hipStream_t stream)
{
    const int*   ids  = (const int*)  d_in[0];
    const float* h0   = (const float*)d_in[1];
    const float* c0   = (const float*)d_in[2];
    const float* E    = (const float*)d_in[3];
    const float* Wih0 = (const float*)d_in[4];
    const float* Whh0 = (const float*)d_in[5];
    const float* bih0 = (const float*)d_in[6];
    const float* bhh0 = (const float*)d_in[7];
    const float* Wih1 = (const float*)d_in[8];
    const float* Whh1 = (const float*)d_in[9];
    const float* bih1 = (const float*)d_in[10];
    const float* bhh1 = (const float*)d_in[11];
    const float* Wg   = (const float*)d_in[12];
    const float* bg   = (const float*)d_in[13];
    const float* mt   = (const float*)d_in[14];
    const float* mwt  = (const float*)d_in[15];
    const float* sb   = (const float*)d_in[16];
    const int*   widx = (const int*)  d_in[17];
    const float* M1   = (const float*)d_in[18];
    const float* M2   = (const float*)d_in[19];

    float* out      = (float*)d_out;
    float* out_word = out;                               // [N,V]
    float* out_gate = out + (size_t)N_ * V_;             // [N,S]
    float* out_h    = out_gate + (size_t)N_ * S_;        // [2,B,H]
    float* out_c    = out_h + 2 * B_ * H_;               // [2,B,H]

    float* ws = (float*)d_ws;
    float* emb     = ws; ws += (size_t)N_ * H_;          // 524288
    float* zx      = ws; ws += (size_t)N_ * G4;          // 2097152
    float* y0      = ws; ws += (size_t)N_ * H_;
    float* y1      = ws; ws += (size_t)N_ * H_;
    float* cb0     = ws; ws += B_ * H_;
    float* cb1     = ws; ws += B_ * H_;
    float* transed = ws; ws += (size_t)K_ * N_ * H_;     // 2621440
    float* ctxT    = ws; ws += (size_t)Z_ * H_;          // 10240000
    float* logits  = ws; ws += (size_t)N_ * Z_;          // 20480000
    float* smw     = ws; ws += ((size_t)K_ * S_ + 3) & ~(size_t)3;

    // gathers + basis softmax (independent of LSTM)
    gather_rows4<<<(N_ * (H_ / 4) + 255) / 256, 256, 0, stream>>>(E, ids, emb, N_);
    gather_rows4<<<(Z_ * (H_ / 4) + 255) / 256, 256, 0, stream>>>(E, widx, ctxT, Z_);
    smw_softmax<<<(S_ + 255) / 256, 256, 0, stream>>>(mwt, smw);

    // ---- layer 0: Zx = emb @ Wih0^T + bih0 + bhh0, then 32 recurrent steps
    gemm64<true, 0><<<dim3(G4 / 64, N_ / 64), 256, 0, stream>>>(
        emb, Wih0, bih0, bhh0, zx, N_, G4, H_);
    for (int t = 0; t < T_; ++t) {
        const float* hp = t ? (y0 + (size_t)(t - 1) * B_ * H_) : h0;
        const float* ci = t ? cb0 : c0;
        lstm_step<<<dim3(32, 4), 256, 0, stream>>>(
            zx + (size_t)t * B_ * G4, hp, Whh0, ci, cb0, y0 + (size_t)t * B_ * H_);
    }
    // ---- layer 1
    gemm64<true, 0><<<dim3(G4 / 64, N_ / 64), 256, 0, stream>>>(
        y0, Wih1, bih1, bhh1, zx, N_, G4, H_);
    for (int t = 0; t < T_; ++t) {
        const float* hp = t ? (y1 + (size_t)(t - 1) * B_ * H_) : (h0 + B_ * H_);
        const float* ci = t ? cb1 : (c0 + B_ * H_);
        lstm_step<<<dim3(32, 4), 256, 0, stream>>>(
            zx + (size_t)t * B_ * G4, hp, Whh1, ci, cb1, y1 + (size_t)t * B_ * H_);
    }

    // gate = sigmoid(out @ Wg^T + bg)  -> straight into d_out
    gemm64<true, 1><<<dim3((S_ + 63) / 64, N_ / 64), 256, 0, stream>>>(
        y1, Wg, bg, nullptr, out_gate, N_, S_, H_);

    // transed[k] = out @ multi_trans[k]   (B is [H][H] row-major, NN)
    for (int k = 0; k < K_; ++k)
        gemm64<false, 0><<<dim3(H_ / 64, N_ / 64), 256, 0, stream>>>(
            y1, mt + (size_t)k * H_ * H_, nullptr, nullptr,
            transed + (size_t)k * N_ * H_, N_, H_, H_);

    // fused: logits[n][z] = sum_k ml*mc + sense_bias
    fused_logits<<<dim3((Z_ + 63) / 64, N_ / 64), 256, 0, stream>>>(
        transed, ctxT, out_gate, smw, M1, sb, logits);

    // sense_prob = softmax(logits) in place
    softmax_rows<<<N_, 256, 0, stream>>>(logits);

    // word_prob = sense_prob @ M2  (NN)
    gemm64<false, 0><<<dim3((V_ + 63) / 64, N_ / 64), 256, 0, stream>>>(
        logits, M2, nullptr, nullptr, out_word, N_, V_, Z_);

    copy_hc<<<(B_ * H_ + 255) / 256, 256, 0, stream>>>(y0, y1, cb0, cb1, out_h, out_c);
}